// Round 2
// baseline (107.926 us; speedup 1.0000x reference)
//
#include <hip/hip_runtime.h>
#include <math.h>

// Capsule conv + dynamic routing via fp16 MFMA (16x16x32), swapped operands:
// A = prepped fp16 weights (M = f), B = LDS input patch (N = px).
// R13 change (resubmit after infra flake): each block computes TWO output rows
// (h, h+1) -> four px-tiles (Mt 0..3) per A-fragment. Weight L2 traffic halves
// again (327->164 MB) and each in-flight A-load feeds 4 MFMAs. Cost: acc=128
// regs -> launch_bounds(512,2) = 256-reg budget, 1 block/CU (8 waves).
// Grid 1024->512. Softmax phase now uses all 512 threads (64 px x 8 i tasks).
// NOTE: hipLaunchCooperativeKernel is NOT graph-capturable here (R7 failed);
// on-the-fly fp32 weight loads are latency-bound (R9). ~44us d_ws re-poison
// fill + ~12us restore/launch are fixed harness overhead.
//
// x:    [B=32][H=32][W=32][128] fp32 (128 = i*16+cin)
// wts:  [i=8][k=144][o=128] fp32 -> w16[(i*5+q)][c][lane][j]
//       = wts[(i*144 + q*32 + (lane>>4)*8 + j)*128 + c*16 + (lane&15)], 0 for k>=144
// out:  [B][H][W][128] fp32 (o = c*16+f)
//
// Block = 512 = 8 waves = c 0..7, 2 rows x 32 px; grid = 512 (b*16+h2), h=2*h2.
// MFMA 16x16x32: A[m=lane&15 -> f][k=quad*8+j], B[k][n=lane&15 -> px(mt)].
// D: px = (mt&1)*16 + lane&15, row = h+(mt>>1), f = quad*4 + reg.

typedef _Float16 fp16x8 __attribute__((ext_vector_type(8)));
typedef float f32x4 __attribute__((ext_vector_type(4)));

#define EPS 1e-7f
constexpr int PSTRIDE = 136;   // fp16 elems; 272B row stride: 16B-aligned, 2-way banks (free)
constexpr int PCOLS   = 34;    // 32 px + 2 halo
constexpr int PROWS   = 4;     // rows h-1..h+2
constexpr int LSTRIDE = 76;    // lg_arr: [px*76 + i*9 + c]
constexpr int PXS     = 76;    // r_arr:  [px*76 + c*8 + i]; b128 stride 304B -> 2-way (free)
constexpr int W_ELEMS = 40 * 8 * 64 * 8;   // 163840

// sum across the 4 quads (lanes ^16, ^32); all lanes receive the total
__device__ __forceinline__ float sumquad(float v) {
    v += __shfl_xor(v, 16);
    v += __shfl_xor(v, 32);
    return v;
}

// prep: direct scatter, 640 blocks x 256 threads, 1 element each (R8-proven).
__global__ __launch_bounds__(256)
void prep_weights(const float* __restrict__ wts,
                  _Float16* __restrict__ w16) {
    int n = blockIdx.x * 256 + threadIdx.x;        // 0..163839
    if (n >= W_ELEMS) return;
    int j    = n & 7;
    int ln   = (n >> 3) & 63;
    int c0   = (n >> 9) & 7;
    int iq   = n >> 12;                            // i*5+q
    int i0   = iq / 5;
    int q0   = iq - i0 * 5;
    int k = q0 * 32 + (ln >> 4) * 8 + j;
    float w = 0.f;
    if (k < 144) w = wts[(i0 * 144 + k) * 128 + c0 * 16 + (ln & 15)];
    w16[n] = (_Float16)w;                          // RNE
}

__global__ __launch_bounds__(512, 2)
void capsule_mfma_kernel(const float* __restrict__ x,
                         const _Float16* __restrict__ w16,
                         const float* __restrict__ bias,
                         float* __restrict__ out)
{
    __shared__ _Float16 patch[PROWS * PCOLS * PSTRIDE];  // 36992 B
    __shared__ float lg_arr[64 * LSTRIDE];               // 19456 B
    __shared__ float r_arr[64 * PXS];                    // 19456 B

    const int tid  = threadIdx.x;
    const int lane = tid & 63;
    const int c    = tid >> 6;     // wave = c
    const int l15  = lane & 15;    // A: f ; B & D: px-in-tile
    const int quad = lane >> 4;
    const int lane8 = lane * 8;

    const int bid = blockIdx.x;
    const int h2 = bid & 15, b = bid >> 4;
    const int h = h2 << 1;         // output rows h, h+1

    // ---- stage input patch rows h-1..h+2, cols -1..32, fp16 ----
    const float4* x4 = (const float4*)x;
    for (int idx = tid; idx < PROWS * PCOLS * 32; idx += 512) {
        int ch4  = idx & 31;
        int slot = idx >> 5;               // row*34 + colp
        int row  = slot / PCOLS;
        int colp = slot - row * PCOLS;
        int gh = h - 1 + row;
        int gw = colp - 1;
        float4 v = {0.f, 0.f, 0.f, 0.f};
        if ((unsigned)gh < 32u && (unsigned)gw < 32u)
            v = x4[(((b * 32 + gh) * 32 + gw) << 5) + ch4];
        _Float16 ph[4];
        ph[0] = (_Float16)v.x; ph[1] = (_Float16)v.y;
        ph[2] = (_Float16)v.z; ph[3] = (_Float16)v.w;
        *(ushort4*)&patch[slot * PSTRIDE + ch4 * 4] = *(const ushort4*)ph;
    }
    __syncthreads();

    // ---- B (patch) per-lane offsets: k = q*32 + quad*8 + j; tap = 2q+(quad>>1) ----
    int a_off[5];
    #pragma unroll
    for (int q = 0; q < 5; ++q) {
        int tap = 2 * q + (quad >> 1);
        if (tap > 8) tap = 8;                 // pad region: A is zero there
        int dy = tap / 3, dx = tap - dy * 3;
        a_off[q] = (dy * PCOLS + l15 + dx) * PSTRIDE + (quad & 1) * 8;
    }

    // ---- conv via MFMA: 40 steps of (1 A b128 from L2, 4 B ds_read, 4 MFMA) ----
    f32x4 acc[4][8];
    #pragma unroll
    for (int mt = 0; mt < 4; ++mt)
        #pragma unroll
        for (int i = 0; i < 8; ++i) acc[mt][i] = (f32x4){0.f, 0.f, 0.f, 0.f};

    #pragma unroll
    for (int q = 0; q < 5; ++q) {
        #pragma unroll
        for (int i = 0; i < 8; ++i) {
            int woff = ((i * 5 + q) * 8 + c) * 512 + lane8;
            fp16x8 aw = *(const fp16x8*)(w16 + woff);
            fp16x8 b0 = *(const fp16x8*)(patch + a_off[q] + i * 16);
            fp16x8 b1 = *(const fp16x8*)(patch + a_off[q] + 16 * PSTRIDE + i * 16);
            fp16x8 b2 = *(const fp16x8*)(patch + a_off[q] + 34 * PSTRIDE + i * 16);
            fp16x8 b3 = *(const fp16x8*)(patch + a_off[q] + 50 * PSTRIDE + i * 16);
            acc[0][i] = __builtin_amdgcn_mfma_f32_16x16x32_f16(aw, b0, acc[0][i], 0, 0, 0);
            acc[1][i] = __builtin_amdgcn_mfma_f32_16x16x32_f16(aw, b1, acc[1][i], 0, 0, 0);
            acc[2][i] = __builtin_amdgcn_mfma_f32_16x16x32_f16(aw, b2, acc[2][i], 0, 0, 0);
            acc[3][i] = __builtin_amdgcn_mfma_f32_16x16x32_f16(aw, b3, acc[3][i], 0, 0, 0);
        }
    }

    // ---- dynamic routing: thread owns (px-tile mt, c, f = quad*4 + 0..3) ----
    // pxid(mt) = (mt>>1)*32 + (mt&1)*16 + l15
    const float4 bb4 = *(const float4*)(bias + c * 16 + quad * 4);
    const float barr[4] = {bb4.x, bb4.y, bb4.z, bb4.w};

    float actv[4][4];

    // iter 0: route = 1/8 uniform
    #pragma unroll
    for (int mt = 0; mt < 4; ++mt) {
        float pre[4];
        #pragma unroll
        for (int r = 0; r < 4; ++r) {
            float s = acc[mt][0][r] + acc[mt][1][r] + acc[mt][2][r] + acc[mt][3][r]
                    + acc[mt][4][r] + acc[mt][5][r] + acc[mt][6][r] + acc[mt][7][r];
            pre[r] = s * 0.125f + barr[r];
        }
        float s2 = sumquad(pre[0]*pre[0] + pre[1]*pre[1] + pre[2]*pre[2] + pre[3]*pre[3]);
        float scale = s2 * __builtin_amdgcn_rsqf(s2 + EPS) * __builtin_amdgcn_rcpf(1.f + s2);
        #pragma unroll
        for (int r = 0; r < 4; ++r) actv[mt][r] = scale * pre[r];
    }
    #pragma unroll
    for (int mt = 0; mt < 4; ++mt) {
        int pxid = (mt >> 1) * 32 + (mt & 1) * 16 + l15;
        #pragma unroll
        for (int i = 0; i < 8; ++i) {
            float t = acc[mt][i][0]*actv[mt][0] + acc[mt][i][1]*actv[mt][1]
                    + acc[mt][i][2]*actv[mt][2] + acc[mt][i][3]*actv[mt][3];
            t = sumquad(t);
            if (quad == 0) lg_arr[pxid * LSTRIDE + i * 9 + c] = t;
        }
    }
    __syncthreads();
    {   // softmax over c for each (px, i): 64*8 = 512 tasks = all threads
        int p = tid >> 3, ii = tid & 7;
        const float* lrow = &lg_arr[p * LSTRIDE + ii * 9];
        float m = lrow[0];
        #pragma unroll
        for (int cc = 1; cc < 8; ++cc) m = fmaxf(m, lrow[cc]);
        float e[8]; float den = 0.f;
        #pragma unroll
        for (int cc = 0; cc < 8; ++cc) { e[cc] = __expf(lrow[cc] - m); den += e[cc]; }
        float rd = __builtin_amdgcn_rcpf(den);
        #pragma unroll
        for (int cc = 0; cc < 8; ++cc) r_arr[p * PXS + cc * 8 + ii] = e[cc] * rd;
    }
    __syncthreads();

    // iter 1
    #pragma unroll
    for (int mt = 0; mt < 4; ++mt) {
        int pxid = (mt >> 1) * 32 + (mt & 1) * 16 + l15;
        const float4* rp = (const float4*)&r_arr[pxid * PXS + c * 8];
        float4 r0 = rp[0], r1 = rp[1];
        float pre[4];
        #pragma unroll
        for (int r = 0; r < 4; ++r) {
            float s;
            s  = r0.x * acc[mt][0][r]; s = fmaf(r0.y, acc[mt][1][r], s);
            s  = fmaf(r0.z, acc[mt][2][r], s); s = fmaf(r0.w, acc[mt][3][r], s);
            s  = fmaf(r1.x, acc[mt][4][r], s); s = fmaf(r1.y, acc[mt][5][r], s);
            s  = fmaf(r1.z, acc[mt][6][r], s); s = fmaf(r1.w, acc[mt][7][r], s);
            pre[r] = s + barr[r];
        }
        float s2 = sumquad(pre[0]*pre[0] + pre[1]*pre[1] + pre[2]*pre[2] + pre[3]*pre[3]);
        float scale = s2 * __builtin_amdgcn_rsqf(s2 + EPS) * __builtin_amdgcn_rcpf(1.f + s2);
        #pragma unroll
        for (int r = 0; r < 4; ++r) actv[mt][r] = scale * pre[r];
    }
    #pragma unroll
    for (int mt = 0; mt < 4; ++mt) {
        int pxid = (mt >> 1) * 32 + (mt & 1) * 16 + l15;
        #pragma unroll
        for (int i = 0; i < 8; ++i) {
            float t = acc[mt][i][0]*actv[mt][0] + acc[mt][i][1]*actv[mt][1]
                    + acc[mt][i][2]*actv[mt][2] + acc[mt][i][3]*actv[mt][3];
            t = sumquad(t);
            if (quad == 0) lg_arr[pxid * LSTRIDE + i * 9 + c] += t;
        }
    }
    __syncthreads();
    {
        int p = tid >> 3, ii = tid & 7;
        const float* lrow = &lg_arr[p * LSTRIDE + ii * 9];
        float m = lrow[0];
        #pragma unroll
        for (int cc = 1; cc < 8; ++cc) m = fmaxf(m, lrow[cc]);
        float e[8]; float den = 0.f;
        #pragma unroll
        for (int cc = 0; cc < 8; ++cc) { e[cc] = __expf(lrow[cc] - m); den += e[cc]; }
        float rd = __builtin_amdgcn_rcpf(den);
        #pragma unroll
        for (int cc = 0; cc < 8; ++cc) r_arr[p * PXS + cc * 8 + ii] = e[cc] * rd;
    }
    __syncthreads();

    // iter 2: final activation -> out (per-lane float4: f = quad*4 + 0..3)
    #pragma unroll
    for (int mt = 0; mt < 4; ++mt) {
        int pxid = (mt >> 1) * 32 + (mt & 1) * 16 + l15;
        const float4* rp = (const float4*)&r_arr[pxid * PXS + c * 8];
        float4 r0 = rp[0], r1 = rp[1];
        float pre[4];
        #pragma unroll
        for (int r = 0; r < 4; ++r) {
            float s;
            s  = r0.x * acc[mt][0][r]; s = fmaf(r0.y, acc[mt][1][r], s);
            s  = fmaf(r0.z, acc[mt][2][r], s); s = fmaf(r0.w, acc[mt][3][r], s);
            s  = fmaf(r1.x, acc[mt][4][r], s); s = fmaf(r1.y, acc[mt][5][r], s);
            s  = fmaf(r1.z, acc[mt][6][r], s); s = fmaf(r1.w, acc[mt][7][r], s);
            pre[r] = s + barr[r];
        }
        float s2 = sumquad(pre[0]*pre[0] + pre[1]*pre[1] + pre[2]*pre[2] + pre[3]*pre[3]);
        float scale = s2 * __builtin_amdgcn_rsqf(s2 + EPS) * __builtin_amdgcn_rcpf(1.f + s2);
        float4 o4 = { scale*pre[0], scale*pre[1], scale*pre[2], scale*pre[3] };
        int gw = (mt & 1) * 16 + l15;
        int gh = h + (mt >> 1);
        *(float4*)(out + (((b * 32 + gh) * 32 + gw) << 7) + c * 16 + quad * 4) = o4;
    }
}

extern "C" void kernel_launch(void* const* d_in, const int* in_sizes, int n_in,
                              void* d_out, int out_size, void* d_ws, size_t ws_size,
                              hipStream_t stream) {
    const float* x    = (const float*)d_in[0];
    const float* wts  = (const float*)d_in[1];
    const float* bias = (const float*)d_in[2];
    float* out        = (float*)d_out;
    _Float16* w16     = (_Float16*)d_ws;

    prep_weights<<<dim3(640), dim3(256), 0, stream>>>(wts, w16);
    capsule_mfma_kernel<<<dim3(512), dim3(512), 0, stream>>>(x, w16, bias, out);
}

// Round 3
// 105.252 us; speedup vs baseline: 1.0254x; 1.0254x over previous
//
#include <hip/hip_runtime.h>
#include <math.h>

// Capsule conv + dynamic routing via fp16 MFMA (16x16x32), swapped operands:
// A = prepped fp16 weights (M = f), B = LDS input patch (N = px).
// R14: back to R12 geometry (1 row, Mt=2, grid 1024, acc=64 AGPR), but the
// A-stream is now staged through a per-wave 3-deep LDS ring via
// global_load_lds + counted s_waitcnt vmcnt(2) (T3/T4 pattern). In-flight
// A storage moves from VGPRs to LDS -> deep MLP at zero register cost and
// ZERO barriers (wave c stages its own chunk; stage->consume is wave-local).
// R13 post-mortem: 240 regs -> 1 block/CU, A-loads serialized at ~350cy/step
// (one L2 latency each), MfmaUtil 8.4%. The A ring (32KB) is unioned with
// the routing arrays (used only after conv; one barrier separates).
// NOTE: hipLaunchCooperativeKernel is NOT graph-capturable here (R7 failed);
// ~44us d_ws re-poison fill + ~12us restore/launch are fixed harness overhead.
//
// x:    [B=32][H=32][W=32][128] fp32 (128 = i*16+cin)
// wts:  [i=8][k=144][o=128] fp32 -> w16[(i*5+q)][c][lane][j]
//       = wts[(i*144 + q*32 + (lane>>4)*8 + j)*128 + c*16 + (lane&15)], 0 for k>=144
// out:  [B][H][W][128] fp32 (o = c*16+f)
//
// Block = 512 = 8 waves = c 0..7, full 32-px row; grid = 1024 (b*32+h).
// Conv loop: chunk ch = i*5+q (memory-linear in w16); per step:
//   vmcnt(2) -> ds_read A (own 16B) + 2 B ds_reads -> 2 MFMA -> issue ch+3.
// LDS: patch 27744 + union(Abuf 4x8x1KB = 32768 | lg 9728 + r 9728) = 60512 B
// -> 2 blocks/CU; regs ~64 AGPR + ~60 VGPR -> 4 waves/EU (launch_bounds 512,4).

typedef _Float16 fp16x8 __attribute__((ext_vector_type(8)));
typedef float f32x4 __attribute__((ext_vector_type(4)));

#define EPS 1e-7f
constexpr int PSTRIDE = 136;   // fp16 elems; 272B row stride: 16B-aligned, 2-way banks (free)
constexpr int PCOLS   = 34;    // 32 px + 2 halo
constexpr int LSTRIDE = 76;    // lg_arr: [px*76 + i*9 + c]
constexpr int PXS     = 76;    // r_arr:  [px*76 + c*8 + i]; b128 stride 304B -> 2-way (free)
constexpr int W_ELEMS = 40 * 8 * 64 * 8;   // 163840

// sum across the 4 quads (lanes ^16, ^32); all lanes receive the total
__device__ __forceinline__ float sumquad(float v) {
    v += __shfl_xor(v, 16);
    v += __shfl_xor(v, 32);
    return v;
}

// async global->LDS, 16B per lane: LDS dest = wave-uniform base + lane*16
__device__ __forceinline__ void gll16(const _Float16* g, _Float16* l) {
    __builtin_amdgcn_global_load_lds(
        (const __attribute__((address_space(1))) unsigned int*)(const void*)g,
        (__attribute__((address_space(3))) unsigned int*)(void*)l, 16, 0, 0);
}

// prep: direct scatter, 640 blocks x 256 threads, 1 element each (R8-proven).
__global__ __launch_bounds__(256)
void prep_weights(const float* __restrict__ wts,
                  _Float16* __restrict__ w16) {
    int n = blockIdx.x * 256 + threadIdx.x;        // 0..163839
    if (n >= W_ELEMS) return;
    int j    = n & 7;
    int ln   = (n >> 3) & 63;
    int c0   = (n >> 9) & 7;
    int iq   = n >> 12;                            // i*5+q
    int i0   = iq / 5;
    int q0   = iq - i0 * 5;
    int k = q0 * 32 + (ln >> 4) * 8 + j;
    float w = 0.f;
    if (k < 144) w = wts[(i0 * 144 + k) * 128 + c0 * 16 + (ln & 15)];
    w16[n] = (_Float16)w;                          // RNE
}

__global__ __launch_bounds__(512, 4)
void capsule_mfma_kernel(const float* __restrict__ x,
                         const _Float16* __restrict__ w16,
                         const float* __restrict__ bias,
                         float* __restrict__ out)
{
    __shared__ _Float16 patch[3 * PCOLS * PSTRIDE];      // 27744 B
    // union: A ring buffer during conv | routing arrays after conv
    __shared__ __align__(16) unsigned char smem_u[32768];
    _Float16 (*Abuf)[8][512] = (_Float16 (*)[8][512])(void*)smem_u;  // [slot][c][512]
    float* lg_arr = (float*)(void*)smem_u;               // 32*76*4 = 9728 B
    float* r_arr  = (float*)(void*)(smem_u + 9728);      // 9728 B

    const int tid  = threadIdx.x;
    const int lane = tid & 63;
    const int c    = tid >> 6;     // wave = c
    const int l15  = lane & 15;    // A: f ; B & D: px-in-tile
    const int quad = lane >> 4;
    const int lane8 = lane * 8;

    const int bid = blockIdx.x;
    const int h = bid & 31, b = bid >> 5;

    // ---- stage input patch rows h-1..h+1, cols -1..32, fp16 ----
    const float4* x4 = (const float4*)x;
    for (int idx = tid; idx < 3 * PCOLS * 32; idx += 512) {
        int ch4  = idx & 31;
        int slot = idx >> 5;               // row*34 + colp
        int row  = slot / PCOLS;
        int colp = slot - row * PCOLS;
        int gh = h - 1 + row;
        int gw = colp - 1;
        float4 v = {0.f, 0.f, 0.f, 0.f};
        if ((unsigned)gh < 32u && (unsigned)gw < 32u)
            v = x4[(((b * 32 + gh) * 32 + gw) << 5) + ch4];
        _Float16 ph[4];
        ph[0] = (_Float16)v.x; ph[1] = (_Float16)v.y;
        ph[2] = (_Float16)v.z; ph[3] = (_Float16)v.w;
        *(ushort4*)&patch[slot * PSTRIDE + ch4 * 4] = *(const ushort4*)ph;
    }
    __syncthreads();

    // ---- B (patch) per-lane offsets: k = q*32 + quad*8 + j; tap = 2q+(quad>>1) ----
    int a_off[5];
    #pragma unroll
    for (int q = 0; q < 5; ++q) {
        int tap = 2 * q + (quad >> 1);
        if (tap > 8) tap = 8;                 // pad region: A is zero there
        int dy = tap / 3, dx = tap - dy * 3;
        a_off[q] = (dy * PCOLS + l15 + dx) * PSTRIDE + (quad & 1) * 8;
    }

    // ---- bias preload + drain so vmcnt counts ONLY the A-ring DMAs ----
    const float4 bb4 = *(const float4*)(bias + c * 16 + quad * 4);
    const float barr[4] = {bb4.x, bb4.y, bb4.z, bb4.w};
    asm volatile("s_waitcnt vmcnt(0)" ::: "memory");

    // ---- conv: 40 chunks (ch = i*5+q, memory-linear), 3-deep LDS A-ring ----
    const _Float16* gsrc = w16 + c * 512 + lane8;   // + ch*4096

    gll16(gsrc + 0 * 4096, &Abuf[0][c][0]);
    gll16(gsrc + 1 * 4096, &Abuf[1][c][0]);
    gll16(gsrc + 2 * 4096, &Abuf[2][c][0]);

    f32x4 acc[2][8];
    #pragma unroll
    for (int mt = 0; mt < 2; ++mt)
        #pragma unroll
        for (int i = 0; i < 8; ++i) acc[mt][i] = (f32x4){0.f, 0.f, 0.f, 0.f};

    #pragma unroll
    for (int ch = 0; ch < 40; ++ch) {
        if (ch < 38)       asm volatile("s_waitcnt vmcnt(2)" ::: "memory");
        else if (ch == 38) asm volatile("s_waitcnt vmcnt(1)" ::: "memory");
        else               asm volatile("s_waitcnt vmcnt(0)" ::: "memory");
        const int i = ch / 5;
        const int q = ch - i * 5;
        fp16x8 aw = *(const fp16x8*)&Abuf[ch & 3][c][lane8];
        fp16x8 b0 = *(const fp16x8*)(patch + a_off[q] + i * 16);
        fp16x8 b1 = *(const fp16x8*)(patch + a_off[q] + 16 * PSTRIDE + i * 16);
        acc[0][i] = __builtin_amdgcn_mfma_f32_16x16x32_f16(aw, b0, acc[0][i], 0, 0, 0);
        acc[1][i] = __builtin_amdgcn_mfma_f32_16x16x32_f16(aw, b1, acc[1][i], 0, 0, 0);
        if (ch + 3 < 40)
            gll16(gsrc + (ch + 3) * 4096, &Abuf[(ch + 3) & 3][c][0]);
    }
    __syncthreads();   // all waves' A-ring reads done before routing reuses the union

    // ---- dynamic routing: thread owns (px = mt*16+l15, c, f = quad*4 + 0..3) ----
    float actv[2][4];

    // iter 0: route = 1/8 uniform
    #pragma unroll
    for (int mt = 0; mt < 2; ++mt) {
        float pre[4];
        #pragma unroll
        for (int r = 0; r < 4; ++r) {
            float s = acc[mt][0][r] + acc[mt][1][r] + acc[mt][2][r] + acc[mt][3][r]
                    + acc[mt][4][r] + acc[mt][5][r] + acc[mt][6][r] + acc[mt][7][r];
            pre[r] = s * 0.125f + barr[r];
        }
        float s2 = sumquad(pre[0]*pre[0] + pre[1]*pre[1] + pre[2]*pre[2] + pre[3]*pre[3]);
        float scale = s2 * __builtin_amdgcn_rsqf(s2 + EPS) * __builtin_amdgcn_rcpf(1.f + s2);
        #pragma unroll
        for (int r = 0; r < 4; ++r) actv[mt][r] = scale * pre[r];
    }
    #pragma unroll
    for (int mt = 0; mt < 2; ++mt)
        #pragma unroll
        for (int i = 0; i < 8; ++i) {
            float t = acc[mt][i][0]*actv[mt][0] + acc[mt][i][1]*actv[mt][1]
                    + acc[mt][i][2]*actv[mt][2] + acc[mt][i][3]*actv[mt][3];
            t = sumquad(t);
            if (quad == 0) lg_arr[(mt * 16 + l15) * LSTRIDE + i * 9 + c] = t;
        }
    __syncthreads();
    if (tid < 256) {   // softmax over c for each (px, i)
        int p = tid >> 3, ii = tid & 7;
        const float* lrow = &lg_arr[p * LSTRIDE + ii * 9];
        float m = lrow[0];
        #pragma unroll
        for (int cc = 1; cc < 8; ++cc) m = fmaxf(m, lrow[cc]);
        float e[8]; float den = 0.f;
        #pragma unroll
        for (int cc = 0; cc < 8; ++cc) { e[cc] = __expf(lrow[cc] - m); den += e[cc]; }
        float rd = __builtin_amdgcn_rcpf(den);
        #pragma unroll
        for (int cc = 0; cc < 8; ++cc) r_arr[p * PXS + cc * 8 + ii] = e[cc] * rd;
    }
    __syncthreads();

    // iter 1
    #pragma unroll
    for (int mt = 0; mt < 2; ++mt) {
        const float4* rp = (const float4*)&r_arr[(mt * 16 + l15) * PXS + c * 8];
        float4 r0 = rp[0], r1 = rp[1];
        float pre[4];
        #pragma unroll
        for (int r = 0; r < 4; ++r) {
            float s;
            s  = r0.x * acc[mt][0][r]; s = fmaf(r0.y, acc[mt][1][r], s);
            s  = fmaf(r0.z, acc[mt][2][r], s); s = fmaf(r0.w, acc[mt][3][r], s);
            s  = fmaf(r1.x, acc[mt][4][r], s); s = fmaf(r1.y, acc[mt][5][r], s);
            s  = fmaf(r1.z, acc[mt][6][r], s); s = fmaf(r1.w, acc[mt][7][r], s);
            pre[r] = s + barr[r];
        }
        float s2 = sumquad(pre[0]*pre[0] + pre[1]*pre[1] + pre[2]*pre[2] + pre[3]*pre[3]);
        float scale = s2 * __builtin_amdgcn_rsqf(s2 + EPS) * __builtin_amdgcn_rcpf(1.f + s2);
        #pragma unroll
        for (int r = 0; r < 4; ++r) actv[mt][r] = scale * pre[r];
    }
    #pragma unroll
    for (int mt = 0; mt < 2; ++mt)
        #pragma unroll
        for (int i = 0; i < 8; ++i) {
            float t = acc[mt][i][0]*actv[mt][0] + acc[mt][i][1]*actv[mt][1]
                    + acc[mt][i][2]*actv[mt][2] + acc[mt][i][3]*actv[mt][3];
            t = sumquad(t);
            if (quad == 0) lg_arr[(mt * 16 + l15) * LSTRIDE + i * 9 + c] += t;
        }
    __syncthreads();
    if (tid < 256) {
        int p = tid >> 3, ii = tid & 7;
        const float* lrow = &lg_arr[p * LSTRIDE + ii * 9];
        float m = lrow[0];
        #pragma unroll
        for (int cc = 1; cc < 8; ++cc) m = fmaxf(m, lrow[cc]);
        float e[8]; float den = 0.f;
        #pragma unroll
        for (int cc = 0; cc < 8; ++cc) { e[cc] = __expf(lrow[cc] - m); den += e[cc]; }
        float rd = __builtin_amdgcn_rcpf(den);
        #pragma unroll
        for (int cc = 0; cc < 8; ++cc) r_arr[p * PXS + cc * 8 + ii] = e[cc] * rd;
    }
    __syncthreads();

    // iter 2: final activation -> out (per-lane float4: f = quad*4 + 0..3)
    #pragma unroll
    for (int mt = 0; mt < 2; ++mt) {
        const float4* rp = (const float4*)&r_arr[(mt * 16 + l15) * PXS + c * 8];
        float4 r0 = rp[0], r1 = rp[1];
        float pre[4];
        #pragma unroll
        for (int r = 0; r < 4; ++r) {
            float s;
            s  = r0.x * acc[mt][0][r]; s = fmaf(r0.y, acc[mt][1][r], s);
            s  = fmaf(r0.z, acc[mt][2][r], s); s = fmaf(r0.w, acc[mt][3][r], s);
            s  = fmaf(r1.x, acc[mt][4][r], s); s = fmaf(r1.y, acc[mt][5][r], s);
            s  = fmaf(r1.z, acc[mt][6][r], s); s = fmaf(r1.w, acc[mt][7][r], s);
            pre[r] = s + barr[r];
        }
        float s2 = sumquad(pre[0]*pre[0] + pre[1]*pre[1] + pre[2]*pre[2] + pre[3]*pre[3]);
        float scale = s2 * __builtin_amdgcn_rsqf(s2 + EPS) * __builtin_amdgcn_rcpf(1.f + s2);
        float4 o4 = { scale*pre[0], scale*pre[1], scale*pre[2], scale*pre[3] };
        int px = mt * 16 + l15;
        *(float4*)(out + (((b * 32 + h) * 32 + px) << 7) + c * 16 + quad * 4) = o4;
    }
}

extern "C" void kernel_launch(void* const* d_in, const int* in_sizes, int n_in,
                              void* d_out, int out_size, void* d_ws, size_t ws_size,
                              hipStream_t stream) {
    const float* x    = (const float*)d_in[0];
    const float* wts  = (const float*)d_in[1];
    const float* bias = (const float*)d_in[2];
    float* out        = (float*)d_out;
    _Float16* w16     = (_Float16*)d_ws;

    prep_weights<<<dim3(640), dim3(256), 0, stream>>>(wts, w16);
    capsule_mfma_kernel<<<dim3(1024), dim3(512), 0, stream>>>(x, w16, bias, out);
}